// Round 8
// baseline (444.219 us; speedup 1.0000x reference)
//
#include <hip/hip_runtime.h>
#include <stdint.h>

// CMAALayer fused kernel, MI355X gfx950. Round 11.
// R4-R10: seven structures converge to 266-289us (occupancy 23-45%, weight
// traffic 0.7-2.6GB, 5-10 barriers) -> invariant = per-element attention
// machinery: ~1900 ds_bpermute + f2b soup on the CU-shared LDS pipe.
// Round 11 replaces it with MFMA attention:
//   - scores per (head, 16-tok tile) = ONE mfma_16x16x32 (K=32=head dim):
//     D[key][query] = K-frag x Q-frag. Diagonal lanes (quad==l15>>2) hold
//     each query's 4 group scores -> mask self, softmax, write l-order fp32
//     alpha (sALf) + packed bf16 pairs (sALpk).
//   - PV per unit = 2 mfma: A = alpha-matrix [query][key(pad 32)] assembled
//     from sALpk via 4 static cndmasks (keys 16-31 zero); B = V^T frags
//     (single b128 reads from [dim][tok] layout). D[query][dim] -> AO.
//   - Projections (16 waves, single pass): wave w<8 = head w of (Q,K),
//     w>=8 = head w-8 of (V,R); 32 cols each, swapped-operand MFMA.
//     Q,K written [tok][dim] bf16 (packed b64); V_eff = sigmoid(R)*V in regs
//     then written transposed [dim][tok] (b16) for PV B-frags.
//   - AO overwrites sQ: each (head,tile) unit reads its Q block then writes
//     its AO block -- same-wave ordering, no extra barrier.
//   - Keeps: grid 2048 lockstep (weight-L2 reuse), reg-LN w/ partial
//     exchange, coalesced alpha store, Wo swapped-operand GEMM.
// LDS: sX 33.8K + sQ/AO 33.8K + sK 33.8K + sVT 34.8K + alpha 10.2K +
//      sPT 9.2K = 155.6KB. 1024 thr, __launch_bounds__(1024,4), 5 barriers.

#define D_DIM   256
#define H_NUM   8
#define RT      64
#define NTHR    1024
#define ROWS_TOT 131072
#define Y_SZ    33554432          // 131072*256
#define SCALE_F 0.17677669529663687f
#define W_ELEMS 65536             // 256*256 per matrix
#define WS_NEED (5 * W_ELEMS * 2) // bytes for bf16 weight copy

#define SX_LD   264   // shorts
#define QK_LD   264   // shorts (sQ/sK/sAO rows)
#define VT_LD   68    // shorts (sVT rows: 64 tokens + pad)
#define SP_LD   36    // floats (16 waves x 2 + pad)

typedef __attribute__((ext_vector_type(8))) short bf16x8;
typedef __attribute__((ext_vector_type(4))) float f32x4;

__device__ __forceinline__ float b2f(uint16_t s) {
    union { uint32_t u; float f; } c; c.u = ((uint32_t)s) << 16; return c.f;
}
__device__ __forceinline__ uint16_t f2b(float f) {
    union { float f; uint32_t u; } c; c.f = f;
    return (uint16_t)((c.u + 0x7fffu + ((c.u >> 16) & 1u)) >> 16);
}
__device__ __forceinline__ bf16x8 cvt8(const float* p) {
    const float4 a = *(const float4*)p;
    const float4 b = *(const float4*)(p + 4);
    bf16x8 r;
    r[0] = (short)f2b(a.x); r[1] = (short)f2b(a.y);
    r[2] = (short)f2b(a.z); r[3] = (short)f2b(a.w);
    r[4] = (short)f2b(b.x); r[5] = (short)f2b(b.y);
    r[6] = (short)f2b(b.z); r[7] = (short)f2b(b.w);
    return r;
}
__device__ __forceinline__ uint2 pack4(f32x4 a) {
    uint2 p;
    p.x = (uint32_t)f2b(a[0]) | ((uint32_t)f2b(a[1]) << 16);
    p.y = (uint32_t)f2b(a[2]) | ((uint32_t)f2b(a[3]) << 16);
    return p;
}

// ---------------- K0: weight fp32 -> bf16 conversion ----------------
__global__ __launch_bounds__(256)
void conv_weights(const float* __restrict__ Wq, const float* __restrict__ Wk,
                  const float* __restrict__ Wv, const float* __restrict__ Wr,
                  const float* __restrict__ Wo, uint16_t* __restrict__ dst)
{
    const int m = blockIdx.x >> 6;                 // matrix id 0..4
    const float* src = (m == 0) ? Wq : (m == 1) ? Wk : (m == 2) ? Wv
                     : (m == 3) ? Wr : Wo;
    const int base = (blockIdx.x & 63) * 1024 + threadIdx.x * 4;
    const float4 v = *(const float4*)&src[base];
    uint2 pk;
    pk.x = (uint32_t)f2b(v.x) | ((uint32_t)f2b(v.y) << 16);
    pk.y = (uint32_t)f2b(v.z) | ((uint32_t)f2b(v.w) << 16);
    *(uint2*)&dst[(size_t)m * W_ELEMS + base] = pk;
}

// ---------------- K1: fused layer (MFMA attention) ----------------
template<bool WBF16>
__global__ __launch_bounds__(NTHR, 4)
void cmaa_fused(const float* __restrict__ tok,
                const float* __restrict__ Wq, const float* __restrict__ Wk,
                const float* __restrict__ Wv, const float* __restrict__ Wr,
                const float* __restrict__ Wo,
                const uint16_t* __restrict__ wbf,
                const float* __restrict__ lng, const float* __restrict__ lnb,
                float* __restrict__ outp)
{
    __shared__ __align__(16) uint16_t sX  [RT * SX_LD];        // 33792 B
    __shared__ __align__(16) uint16_t sQ  [RT * QK_LD];        // 33792 B (-> AO)
    __shared__ __align__(16) uint16_t sK  [RT * QK_LD];        // 33792 B
    __shared__ __align__(16) uint16_t sVT [D_DIM * VT_LD];     // 34816 B
    __shared__ __align__(16) float    sALf[RT * H_NUM * 3];    // 6144 B
    __shared__ __align__(16) uint2    sALpk[RT * H_NUM];       // 4096 B
    __shared__ __align__(16) float    sPT [RT * SP_LD];        // 9216 B

    const int tid  = threadIdx.x;
    const int wv   = tid >> 6;        // wave 0..15
    const int lane = tid & 63;
    const int l15  = lane & 15;
    const int quad = lane >> 4;
    const int R0   = blockIdx.x * RT;

    // ---------------- stage 0: X tile -> LDS (bf16) ----------------
    {
        const float* g = tok + (size_t)R0 * D_DIM;
        #pragma unroll
        for (int it = 0; it < 2; ++it) {
            const int t = tid + it * NTHR;
            const int row = t >> 5, c = t & 31;
            *(bf16x8*)&sX[row * SX_LD + c * 8] = cvt8(&g[row * D_DIM + c * 8]);
        }
    }
    __syncthreads();

    // ---------------- projections: 16 waves, single pass ----------------
    // wave w<8: head w of (Q,K); w>=8: head w-8 of (V,R). 32 cols per wave.
    {
        const bool qkw = (wv < 8);
        const int  h   = wv & 7;
        const float*    WF0 = qkw ? Wq : Wv;
        const float*    WF1 = qkw ? Wk : Wr;
        const uint16_t* WB0 = wbf + (size_t)(qkw ? 0 : 2) * W_ELEMS;
        const uint16_t* WB1 = WB0 + W_ELEMS;

        f32x4 acc[2][2][4];   // [matrix][ct][nt]
        #pragma unroll
        for (int m = 0; m < 2; ++m)
            #pragma unroll
            for (int ct = 0; ct < 2; ++ct)
                #pragma unroll
                for (int nt = 0; nt < 4; ++nt)
                    acc[m][ct][nt] = (f32x4){0.f, 0.f, 0.f, 0.f};

        #pragma unroll
        for (int kk = 0; kk < 8; ++kk) {
            const int k0 = kk * 32;
            bf16x8 ax[4];
            #pragma unroll
            for (int nt = 0; nt < 4; ++nt)
                ax[nt] = *(const bf16x8*)&sX[(nt * 16 + l15) * SX_LD + k0 + quad * 8];
            bf16x8 b0[2], b1[2];
            #pragma unroll
            for (int ct = 0; ct < 2; ++ct) {
                const int wrow = h * 32 + ct * 16 + l15;
                if constexpr (WBF16) {
                    b0[ct] = *(const bf16x8*)&WB0[(size_t)wrow * D_DIM + k0 + quad * 8];
                    b1[ct] = *(const bf16x8*)&WB1[(size_t)wrow * D_DIM + k0 + quad * 8];
                } else {
                    b0[ct] = cvt8(&WF0[(size_t)wrow * D_DIM + k0 + quad * 8]);
                    b1[ct] = cvt8(&WF1[(size_t)wrow * D_DIM + k0 + quad * 8]);
                }
            }
            #pragma unroll
            for (int ct = 0; ct < 2; ++ct)
                #pragma unroll
                for (int nt = 0; nt < 4; ++nt)
                    acc[0][ct][nt] = __builtin_amdgcn_mfma_f32_16x16x32_bf16(b0[ct], ax[nt], acc[0][ct][nt], 0, 0, 0);
            #pragma unroll
            for (int ct = 0; ct < 2; ++ct)
                #pragma unroll
                for (int nt = 0; nt < 4; ++nt)
                    acc[1][ct][nt] = __builtin_amdgcn_mfma_f32_16x16x32_bf16(b1[ct], ax[nt], acc[1][ct][nt], 0, 0, 0);
        }

        // epilogue. D layout: col=l15(token within nt-tile), row=quad*4+r(dim)
        if (qkw) {
            #pragma unroll
            for (int ct = 0; ct < 2; ++ct)
                #pragma unroll
                for (int nt = 0; nt < 4; ++nt) {
                    const int tk = nt * 16 + l15;
                    const int dc = h * 32 + ct * 16 + quad * 4;
                    *(uint2*)&sQ[tk * QK_LD + dc] = pack4(acc[0][ct][nt]);
                    *(uint2*)&sK[tk * QK_LD + dc] = pack4(acc[1][ct][nt]);
                }
        } else {
            #pragma unroll
            for (int ct = 0; ct < 2; ++ct)
                #pragma unroll
                for (int nt = 0; nt < 4; ++nt)
                    #pragma unroll
                    for (int r = 0; r < 4; ++r) {
                        const float ve = acc[0][ct][nt][r] *
                            (1.f / (1.f + __expf(-acc[1][ct][nt][r])));
                        const int dd = h * 32 + ct * 16 + quad * 4 + r;   // global dim
                        sVT[dd * VT_LD + nt * 16 + l15] = f2b(ve);        // V^T
                    }
        }
    }
    __syncthreads();

    // ---------------- MFMA attention: 32 units (head, 16-tok tile) ----------
    #pragma unroll
    for (int uu = 0; uu < 2; ++uu) {
        const int u  = wv + 16 * uu;
        const int hh = u >> 2;       // head 0..7
        const int tt = u & 3;        // token tile 0..3
        const int tk = tt * 16 + l15;

        // scores: D[key=row][query=col] = sum_d K[key][d] * Q[query][d]
        const bf16x8 kf = *(const bf16x8*)&sK[tk * QK_LD + hh * 32 + quad * 8];
        const bf16x8 qf = *(const bf16x8*)&sQ[tk * QK_LD + hh * 32 + quad * 8];
        f32x4 sc = __builtin_amdgcn_mfma_f32_16x16x32_bf16(
            kf, qf, (f32x4){0.f, 0.f, 0.f, 0.f}, 0, 0, 0);

        // diagonal lanes (quad == l15>>2) hold query l15's 4 group scores
        if (quad == (l15 >> 2)) {
            const int r0 = l15 & 3;   // self position
            float sv[4], e[4];
            #pragma unroll
            for (int r = 0; r < 4; ++r) sv[r] = sc[r] * SCALE_F;
            float mx = -1e30f;
            #pragma unroll
            for (int r = 0; r < 4; ++r) mx = fmaxf(mx, (r == r0) ? -1e30f : sv[r]);
            float sum = 0.f;
            #pragma unroll
            for (int r = 0; r < 4; ++r) {
                e[r] = (r == r0) ? 0.f : __expf(sv[r] - mx);
                sum += e[r];
            }
            const float inv = 1.f / sum;
            float al[4];
            #pragma unroll
            for (int r = 0; r < 4; ++r) al[r] = e[r] * inv;
            float* af = &sALf[(tk * H_NUM + hh) * 3];
            #pragma unroll
            for (int r = 0; r < 4; ++r)
                if (r != r0) af[r - (r > r0 ? 1 : 0)] = al[r];
            uint2 pk;
            pk.x = (uint32_t)f2b(al[0]) | ((uint32_t)f2b(al[1]) << 16);
            pk.y = (uint32_t)f2b(al[2]) | ((uint32_t)f2b(al[3]) << 16);
            sALpk[tk * H_NUM + hh] = pk;
        }

        // PV: A = alpha[query][key(pad32)], B = V^T frags -> D[query][dim]
        const uint2 apk = sALpk[tk * H_NUM + hh];
        const bool qm = (quad == ((l15 >> 3) & 1));   // key-oct holding the group
        const bool hi = (l15 & 4) != 0;               // group at oct offset 4
        union { uint32_t u[4]; bf16x8 v; } A;
        A.u[0] = (qm && !hi) ? apk.x : 0u;
        A.u[1] = (qm && !hi) ? apk.y : 0u;
        A.u[2] = (qm &&  hi) ? apk.x : 0u;
        A.u[3] = (qm &&  hi) ? apk.y : 0u;

        const bf16x8 vb0 = *(const bf16x8*)&sVT[(hh * 32 + l15) * VT_LD + tt * 16 + quad * 8];
        const bf16x8 vb1 = *(const bf16x8*)&sVT[(hh * 32 + 16 + l15) * VT_LD + tt * 16 + quad * 8];
        const f32x4 ao0 = __builtin_amdgcn_mfma_f32_16x16x32_bf16(
            A.v, vb0, (f32x4){0.f, 0.f, 0.f, 0.f}, 0, 0, 0);
        const f32x4 ao1 = __builtin_amdgcn_mfma_f32_16x16x32_bf16(
            A.v, vb1, (f32x4){0.f, 0.f, 0.f, 0.f}, 0, 0, 0);

        // AO over dead Q block (same unit owns read+write)
        #pragma unroll
        for (int r = 0; r < 4; ++r) {
            const int tw = tt * 16 + quad * 4 + r;
            sQ[tw * QK_LD + hh * 32 + l15]      = f2b(ao0[r]);
            sQ[tw * QK_LD + hh * 32 + 16 + l15] = f2b(ao1[r]);
        }
    }
    __syncthreads();

    // ---------------- coalesced attn-prob store ----------------
    if (tid < 384) {
        const float4 v = *(const float4*)&sALf[tid * 4];
        *(float4*)&outp[Y_SZ + (size_t)R0 * 24 + tid * 4] = v;
    }

    // ---------------- AO @ Wo^T (swapped operands, 16 cols/wave) ------------
    f32x4 acc3[4];
    #pragma unroll
    for (int nt = 0; nt < 4; ++nt) acc3[nt] = (f32x4){0.f, 0.f, 0.f, 0.f};

    {
        const uint16_t* WoB = wbf + (size_t)4 * W_ELEMS;
        #pragma unroll
        for (int kk = 0; kk < 8; ++kk) {
            const int k0 = kk * 32;
            bf16x8 ao[4];
            #pragma unroll
            for (int nt = 0; nt < 4; ++nt)
                ao[nt] = *(const bf16x8*)&sQ[(nt * 16 + l15) * QK_LD + k0 + quad * 8];
            bf16x8 wo;
            const int wrow = wv * 16 + l15;
            if constexpr (WBF16)
                wo = *(const bf16x8*)&WoB[(size_t)wrow * D_DIM + k0 + quad * 8];
            else
                wo = cvt8(&Wo[(size_t)wrow * D_DIM + k0 + quad * 8]);
            #pragma unroll
            for (int nt = 0; nt < 4; ++nt)
                acc3[nt] = __builtin_amdgcn_mfma_f32_16x16x32_bf16(wo, ao[nt], acc3[nt], 0, 0, 0);
        }
    }

    // ---------------- residual + LN partials ----------------
    #pragma unroll
    for (int nt = 0; nt < 4; ++nt) {
        const int tk = nt * 16 + l15;
        const ushort4 xv = *(const ushort4*)&sX[tk * SX_LD + wv * 16 + quad * 4];
        acc3[nt][0] += b2f(xv.x); acc3[nt][1] += b2f(xv.y);
        acc3[nt][2] += b2f(xv.z); acc3[nt][3] += b2f(xv.w);
        float s1 = 0.f, s2 = 0.f;
        #pragma unroll
        for (int r = 0; r < 4; ++r) {
            const float y = acc3[nt][r];
            s1 += y; s2 += y * y;
        }
        s1 += __shfl_xor(s1, 16); s1 += __shfl_xor(s1, 32);
        s2 += __shfl_xor(s2, 16); s2 += __shfl_xor(s2, 32);
        if (quad == 0) {
            float2 ps; ps.x = s1; ps.y = s2;
            *(float2*)&sPT[tk * SP_LD + wv * 2] = ps;
        }
    }
    __syncthreads();

    // ---------------- LN finalize + store y ----------------
    #pragma unroll
    for (int nt = 0; nt < 4; ++nt) {
        const int tk = nt * 16 + l15;
        const f32x4* pp = (const f32x4*)&sPT[tk * SP_LD];
        float s1 = 0.f, s2 = 0.f;
        #pragma unroll
        for (int j = 0; j < 8; ++j) {
            const f32x4 q = pp[j];
            s1 += q[0] + q[2];
            s2 += q[1] + q[3];
        }
        const float mean = s1 * (1.f / 256.f);
        const float var  = fmaxf(s2 * (1.f / 256.f) - mean * mean, 0.f);
        const float rstd = rsqrtf(var + 1e-5f);
        float* orow = outp + (size_t)(R0 + tk) * D_DIM;
        const int c0 = wv * 16 + quad * 4;
        const float4 g4 = *(const float4*)&lng[c0];
        const float4 b4 = *(const float4*)&lnb[c0];
        float4 o4;
        o4.x = (acc3[nt][0] - mean) * rstd * g4.x + b4.x;
        o4.y = (acc3[nt][1] - mean) * rstd * g4.y + b4.y;
        o4.z = (acc3[nt][2] - mean) * rstd * g4.z + b4.z;
        o4.w = (acc3[nt][3] - mean) * rstd * g4.w + b4.w;
        *(float4*)&orow[c0] = o4;
    }
}

extern "C" void kernel_launch(void* const* d_in, const int* in_sizes, int n_in,
                              void* d_out, int out_size, void* d_ws, size_t ws_size,
                              hipStream_t stream) {
    (void)in_sizes; (void)n_in; (void)out_size;
    const float* tok = (const float*)d_in[0];
    const float* Wq  = (const float*)d_in[1];
    const float* Wk  = (const float*)d_in[2];
    const float* Wv  = (const float*)d_in[3];
    const float* Wr  = (const float*)d_in[4];
    const float* Wo  = (const float*)d_in[5];
    const float* lng = (const float*)d_in[6];
    const float* lnb = (const float*)d_in[7];
    float* outp = (float*)d_out;
    uint16_t* wbf = (uint16_t*)d_ws;

    dim3 grid(ROWS_TOT / RT), block(NTHR);
    if (ws_size >= (size_t)WS_NEED) {
        conv_weights<<<dim3(320), dim3(256), 0, stream>>>(Wq, Wk, Wv, Wr, Wo, wbf);
        cmaa_fused<true><<<grid, block, 0, stream>>>(
            tok, Wq, Wk, Wv, Wr, Wo, wbf, lng, lnb, outp);
    } else {
        cmaa_fused<false><<<grid, block, 0, stream>>>(
            tok, Wq, Wk, Wv, Wr, Wo, wbf, lng, lnb, outp);
    }
}